// Round 2
// baseline (282.055 us; speedup 1.0000x reference)
//
#include <hip/hip_runtime.h>
#include <hip/hip_bf16.h>

typedef __bf16 bf16_t;
typedef __bf16 bf16x4 __attribute__((ext_vector_type(4)));
typedef __bf16 bf16x8 __attribute__((ext_vector_type(8)));
typedef float  f32x4  __attribute__((ext_vector_type(4)));

// ---------------------------------------------------------------- helpers
__device__ __forceinline__ void gload_lds16(const void* g, void* l)
{
    __builtin_amdgcn_global_load_lds((__attribute__((address_space(1))) void*)g,
                                     (__attribute__((address_space(3))) void*)l,
                                     16, 0, 0);
}

// ---------------------------------------------------------------- fused fp32 -> bf16 casts (x1|x2 -> xcat, W1, W2)
__global__ __launch_bounds__(256) void cast_all(const float* __restrict__ x1, const float* __restrict__ x2,
                                                const float* __restrict__ W1, const float* __restrict__ W2,
                                                bf16_t* __restrict__ xcatb, bf16_t* __restrict__ W1b,
                                                bf16_t* __restrict__ W2b)
{
    const size_t i  = ((size_t)blockIdx.x * 256 + threadIdx.x) * 4;
    const size_t M4 = 1ull << 22;              // 4M elements per region
    const size_t r  = i >> 22;
    const size_t off = i & (M4 - 1);
    const float* src; bf16_t* dst;
    if (r == 0)      { src = x1; dst = xcatb; }
    else if (r == 1) { src = x2; dst = xcatb + M4; }
    else if (r == 2) { src = W1; dst = W1b; }
    else             { src = W2; dst = W2b; }
    f32x4 v = *(const f32x4*)(src + off);
    bf16x4 o;
    o[0] = (bf16_t)v[0]; o[1] = (bf16_t)v[1]; o[2] = (bf16_t)v[2]; o[3] = (bf16_t)v[3];
    *(bf16x4*)(dst + off) = o;
}

// ---------------------------------------------------------------- NT GEMM with prefetch double-buffer + epilogue modes
// C[m,n] = sum_k A[m,k]*B[n,k] + bias[n]; 128x128 tile, BK=64, 4 waves (2x2), 16x16x32 MFMA.
// mode 0: bias only. mode 1: + per-block column sum/sumsq partials (BN stats).
// mode 2: + per-block row argmax partials (packed uint64 keys, diag excluded).
__global__ __launch_bounds__(256, 2) void gemm_bt2(
    const bf16_t* __restrict__ A, const bf16_t* __restrict__ B,
    const float* __restrict__ bias, float* __restrict__ C,
    int nbx, int K, int rows_per_batch, long long b_batch_stride,
    int mode, float* __restrict__ ps, float* __restrict__ ps2,
    unsigned long long* __restrict__ pkey)
{
    __shared__ bf16_t lsA[2][128 * 64];
    __shared__ bf16_t lsB[2][128 * 64];
    const int tid  = threadIdx.x;
    const int lane = tid & 63;
    const int wave = tid >> 6;
    const int wm   = (wave >> 1) * 64;
    const int wn   = (wave & 1) * 64;

    // XCD-aware swizzle: nwg % 8 == 0 (512) -> bijective
    const int nwg = gridDim.x;
    const int cpx = nwg >> 3;
    int bid = blockIdx.x;
    bid = (bid & 7) * cpx + (bid >> 3);
    const int bx = bid % nbx;
    const int by = bid / nbx;
    const int m0 = by * 128;
    const int n0 = bx * 128;
    const int N  = nbx * 128;
    const bf16_t* Bb = B + (long long)(m0 / rows_per_batch) * b_batch_stride;

    f32x4 acc[4][4] = {};

    const int srow = tid >> 3;        // 256 threads cover 32 rows x 8 chunks of 16B
    const int scol = (tid & 7) * 8;

    auto STAGE = [&](int buf, int kt) {
#pragma unroll
        for (int i = 0; i < 4; ++i) {
            const int r = i * 32 + srow;
            // LDS dest = wave-uniform base + lane*16 (linear, required for global_load_lds)
            gload_lds16(A  + (size_t)(m0 + r) * K + kt + scol, &lsA[buf][r * 64 + scol]);
            gload_lds16(Bb + (size_t)(n0 + r) * K + kt + scol, &lsB[buf][r * 64 + scol]);
        }
    };

    auto COMPUTE = [&](int buf) {
        const bf16_t* la = lsA[buf];
        const bf16_t* lb = lsB[buf];
#pragma unroll
        for (int ks = 0; ks < 2; ++ks) {
            const int kk = ks * 32 + (lane >> 4) * 8;
            bf16x8 af[4], bfr[4];
#pragma unroll
            for (int f = 0; f < 4; ++f) {
                af[f]  = *(const bf16x8*)&la[(wm + f * 16 + (lane & 15)) * 64 + kk];
                bfr[f] = *(const bf16x8*)&lb[(wn + f * 16 + (lane & 15)) * 64 + kk];
            }
#pragma unroll
            for (int fm = 0; fm < 4; ++fm)
#pragma unroll
                for (int fn = 0; fn < 4; ++fn)
                    acc[fm][fn] = __builtin_amdgcn_mfma_f32_16x16x32_bf16(af[fm], bfr[fn], acc[fm][fn], 0, 0, 0);
        }
    };

    // prologue
    STAGE(0, 0);
    __syncthreads();
    int cur = 0;
    for (int kt = 64; kt < K; kt += 64) {
        STAGE(cur ^ 1, kt);     // prefetch next tile: in flight across the whole compute phase
        COMPUTE(cur);
        __syncthreads();        // drains vmcnt (prefetch done) + lgkm; protects buffer reuse
        cur ^= 1;
    }
    COMPUTE(cur);

    // ---- C write (+bias). C/D layout: col = lane&15, row = (lane>>4)*4 + reg  [m89-verified]
#pragma unroll
    for (int fm = 0; fm < 4; ++fm) {
        const int rb = m0 + wm + fm * 16 + ((lane >> 4) << 2);
#pragma unroll
        for (int fn = 0; fn < 4; ++fn) {
            const int colg = n0 + wn + fn * 16 + (lane & 15);
            const float bv = bias ? bias[colg] : 0.0f;
#pragma unroll
            for (int r = 0; r < 4; ++r)
                C[(size_t)(rb + r) * N + colg] = acc[fm][fn][r] + bv;
        }
    }

    if (mode == 1) {
        // per-block column sum / sumsq over the 128 rows (2 commutative LDS atomics per col -> deterministic)
        __shared__ float cs[128], cq[128];
        if (tid < 128) { cs[tid] = 0.f; cq[tid] = 0.f; }
        __syncthreads();
#pragma unroll
        for (int fn = 0; fn < 4; ++fn) {
            const int coll = wn + fn * 16 + (lane & 15);
            const float bv = bias[n0 + coll];
            float s = 0.f, q = 0.f;
#pragma unroll
            for (int fm = 0; fm < 4; ++fm)
#pragma unroll
                for (int r = 0; r < 4; ++r) {
                    const float v = acc[fm][fn][r] + bv;
                    s += v; q += v * v;
                }
            s += __shfl_xor(s, 16); q += __shfl_xor(q, 16);
            s += __shfl_xor(s, 32); q += __shfl_xor(q, 32);
            if (lane < 16) { atomicAdd(&cs[coll], s); atomicAdd(&cq[coll], q); }
        }
        __syncthreads();
        if (tid < 128) {
            ps [(size_t)by * 2048 + n0 + tid] = cs[tid];
            ps2[(size_t)by * 2048 + n0 + tid] = cq[tid];
        }
    } else if (mode == 2) {
        // per-block row argmax partial; key = ordered(val)<<32 | ~col (max => max val, tie => min col)
        __shared__ unsigned long long kv[128];
        if (tid < 128) kv[tid] = 0ull;
        __syncthreads();
#pragma unroll
        for (int fm = 0; fm < 4; ++fm)
#pragma unroll
            for (int r = 0; r < 4; ++r) {
                const int rowl = wm + fm * 16 + ((lane >> 4) << 2) + r;
                const int self = (m0 + rowl) & 2047;
                float best = -1.0e38f; int bi = 0x7fffffff;
#pragma unroll
                for (int fn = 0; fn < 4; ++fn) {
                    const int cg = n0 + wn + fn * 16 + (lane & 15);
                    const float v = acc[fm][fn][r];
                    if (cg != self && v > best) { best = v; bi = cg; }
                }
#pragma unroll
                for (int st = 1; st <= 8; st <<= 1) {
                    const float ov = __shfl_xor(best, st);
                    const int   oi = __shfl_xor(bi, st);
                    if (ov > best || (ov == best && oi < bi)) { best = ov; bi = oi; }
                }
                if ((lane & 15) == 0) {
                    unsigned u = __float_as_uint(best);
                    u = (u & 0x80000000u) ? ~u : (u | 0x80000000u);
                    const unsigned long long key = ((unsigned long long)u << 32) | (unsigned)(~bi);
                    atomicMax(&kv[rowl], key);   // 2 commutative/idempotent atomics per row -> deterministic
                }
            }
        __syncthreads();
        if (tid < 128) pkey[(size_t)bx * 4096 + m0 + tid] = kv[tid];
    }
}

// ---------------------------------------------------------------- BN finalize from 16 per-mblock partials
__global__ __launch_bounds__(256) void bn_final2(const float* __restrict__ ps, const float* __restrict__ ps2,
                                                 float* __restrict__ mu, float* __restrict__ rinv)
{
    const int c = blockIdx.x * 256 + threadIdx.x;  // 0..4095
    const int b = c >> 11, col = c & 2047;
    float s = 0.f, s2 = 0.f;
    for (int i = 0; i < 16; ++i) {
        s  += ps [(size_t)(b * 16 + i) * 2048 + col];
        s2 += ps2[(size_t)(b * 16 + i) * 2048 + col];
    }
    const float m = s * (1.0f / 2048.0f);
    const float v = s2 * (1.0f / 2048.0f) - m * m;   // biased var
    mu[c]   = m;
    rinv[c] = rsqrtf(v + 1e-5f);
}

// ---------------------------------------------------------------- BN apply + ReLU + cast to bf16
__global__ __launch_bounds__(256) void bn_apply(const float* __restrict__ h, const float* __restrict__ mu,
                                                const float* __restrict__ rinv, const float* __restrict__ gamma,
                                                const float* __restrict__ beta, bf16_t* __restrict__ out)
{
    const size_t base = ((size_t)blockIdx.x * 256 + threadIdx.x) * 4;
    const int row = (int)(base >> 11);
    const int col = (int)(base & 2047);
    const int br  = row >> 11;
    f32x4 v = *(const f32x4*)(h + base);
    bf16x4 o;
#pragma unroll
    for (int j = 0; j < 4; ++j) {
        const int c = col + j;
        float t = (v[j] - mu[br * 2048 + c]) * rinv[br * 2048 + c] * gamma[c] + beta[c];
        o[j] = (bf16_t)fmaxf(t, 0.0f);
    }
    *(bf16x4*)(out + base) = o;
}

// ---------------------------------------------------------------- row L2-normalize + cast to bf16
__global__ __launch_bounds__(256) void rownorm(const float* __restrict__ o, bf16_t* __restrict__ feat)
{
    const int row = blockIdx.x;
    const int t = threadIdx.x;
    const float* p = o + (size_t)row * 2048;
    f32x4 v0 = *(const f32x4*)(p + t * 4);
    f32x4 v1 = *(const f32x4*)(p + 1024 + t * 4);
    float ss = v0[0]*v0[0] + v0[1]*v0[1] + v0[2]*v0[2] + v0[3]*v0[3]
             + v1[0]*v1[0] + v1[1]*v1[1] + v1[2]*v1[2] + v1[3]*v1[3];
    __shared__ float S[256];
    S[t] = ss;
    __syncthreads();
    for (int off = 128; off; off >>= 1) { if (t < off) S[t] += S[t + off]; __syncthreads(); }
    const float rn = 1.0f / fmaxf(sqrtf(S[0]), 1e-12f);
    bf16x4 o0, o1;
#pragma unroll
    for (int j = 0; j < 4; ++j) { o0[j] = (bf16_t)(v0[j] * rn); o1[j] = (bf16_t)(v1[j] * rn); }
    *(bf16x4*)(feat + (size_t)row * 2048 + t * 4) = o0;
    *(bf16x4*)(feat + (size_t)row * 2048 + 1024 + t * 4) = o1;
}

// ---------------------------------------------------------------- argmax combine over 16 n-block partials
__global__ __launch_bounds__(256) void argmax_combine(const unsigned long long* __restrict__ pkey,
                                                      int* __restrict__ y)
{
    const int row = blockIdx.x * 256 + threadIdx.x;  // 0..4095
    unsigned long long k = 0ull;
    for (int nb = 0; nb < 16; ++nb) {
        const unsigned long long v = pkey[(size_t)nb * 4096 + row];
        k = (v > k) ? v : k;
    }
    y[row] = (int)~((unsigned)(k & 0xFFFFFFFFull));
}

// ---------------------------------------------------------------- connected components via min-propagation (1 block/branch)
__global__ __launch_bounds__(1024) void cc_labels(const int* __restrict__ yg, int* __restrict__ labg)
{
    __shared__ int A_[2048];
    __shared__ int Bn[2048];
    __shared__ int Y_[2048];
    const int br = blockIdx.x;
    const int t = threadIdx.x;
    for (int i = t; i < 2048; i += 1024) { Y_[i] = yg[br * 2048 + i]; A_[i] = i; }
    __syncthreads();
    for (int it = 0; it < 32; ++it) {
        for (int i = t; i < 2048; i += 1024) Bn[i] = min(A_[i], A_[Y_[i]]);   // ln = min(l, l[y])
        __syncthreads();
        for (int i = t; i < 2048; i += 1024) atomicMin(&Bn[Y_[i]], A_[i]);    // ln = ln.at[y].min(l)
        __syncthreads();
        for (int i = t; i < 2048; i += 1024) { int b = Bn[i]; A_[i] = min(b, Bn[b]); } // pointer jump
        __syncthreads();
    }
    for (int i = t; i < 2048; i += 1024) labg[br * 2048 + i] = A_[i];
}

// ---------------------------------------------------------------- per-row contrastive term: lse - possum/poscnt
__global__ __launch_bounds__(256) void loss_rows(const float* __restrict__ sim, const int* __restrict__ labels,
                                                 float* __restrict__ terms)
{
    const int row = blockIdx.x;
    const int br  = row >> 11;
    const int* lab = labels + ((1 - br) << 11);  // mask from the OTHER branch's labels
    const int self = row & 2047;
    const int li = lab[self];
    const int t = threadIdx.x;
    const f32x4* p = (const f32x4*)(sim + (size_t)row * 2048);
    f32x4 a = p[t * 2], b = p[t * 2 + 1];
    float se = 0.f, psum = 0.f; int pc = 0;
#pragma unroll
    for (int j = 0; j < 8; ++j) {
        const int c = t * 8 + j;
        const float v = (j < 4) ? a[j] : b[j - 4];
        if (c == self) continue;
        const float lg = v * 10.0f;   // 1/T
        se += expf(lg);
        if (lab[c] == li) { psum += lg; pc++; }
    }
    __shared__ float SE[256], PS[256]; __shared__ int PC[256];
    SE[t] = se; PS[t] = psum; PC[t] = pc;
    __syncthreads();
    for (int off = 128; off; off >>= 1) {
        if (t < off) { SE[t] += SE[t + off]; PS[t] += PS[t + off]; PC[t] += PC[t + off]; }
        __syncthreads();
    }
    if (t == 0) terms[row] = logf(SE[0]) - PS[0] / (float)PC[0];
}

// ---------------------------------------------------------------- final deterministic reduce
__global__ __launch_bounds__(1024) void final_reduce(const float* __restrict__ terms, float* __restrict__ out)
{
    const int t = threadIdx.x;
    float s = terms[t] + terms[t + 1024] + terms[t + 2048] + terms[t + 3072];
    __shared__ float S[1024];
    S[t] = s;
    __syncthreads();
    for (int off = 512; off; off >>= 1) { if (t < off) S[t] += S[t + off]; __syncthreads(); }
    if (t == 0) out[0] = S[0] * (1.0f / 4096.0f);   // (L1+L2)/2, each mean over 2048 rows
}

// ---------------------------------------------------------------- launch
extern "C" void kernel_launch(void* const* d_in, const int* in_sizes, int n_in,
                              void* d_out, int out_size, void* d_ws, size_t ws_size,
                              hipStream_t stream)
{
    const float* x1    = (const float*)d_in[0];
    const float* x2    = (const float*)d_in[1];
    const float* W1    = (const float*)d_in[2];
    const float* b1    = (const float*)d_in[3];
    const float* gamma = (const float*)d_in[4];
    const float* beta  = (const float*)d_in[5];
    const float* W2    = (const float*)d_in[6];
    const float* b2    = (const float*)d_in[7];

    char* ws = (char*)d_ws;
    const size_t MB = 1024ull * 1024ull;
    const size_t NN = 2048ull * 2048ull;
    // Region plan (reuse as regions go dead):
    //  [0,8M)   W1b      (dead after GEMM1)
    //  [8,16M)  W2b      (dead after GEMM2)
    //  [16,32M) xcatb -> hnb (xcatb dead after GEMM1; hnb dead after GEMM2)
    //  [32,64M) h -> o   (dead after rownorm)
    //  [0,32M)  sim      (written by GEMM3 after W1b/W2b/hnb dead)
    //  [64,80M) featb
    //  [80M..)  partials + small buffers
    bf16_t* W1b    = (bf16_t*)(ws + 0);
    bf16_t* W2b    = (bf16_t*)(ws + 8 * MB);
    bf16_t* xcatb  = (bf16_t*)(ws + 16 * MB);
    bf16_t* hnb    = (bf16_t*)(ws + 16 * MB);
    float*  hbuf   = (float*)(ws + 32 * MB);
    float*  sim    = (float*)(ws + 0);
    bf16_t* featb  = (bf16_t*)(ws + 64 * MB);
    float*  psA    = (float*)(ws + 80 * MB);              // [32][2048] col sums
    float*  psB    = psA + 32 * 2048;                      // [32][2048] col sumsq
    float*  mu     = psB + 32 * 2048;                      // [2][2048]
    float*  rinv   = mu + 4096;
    unsigned long long* pkey = (unsigned long long*)(rinv + 4096);  // [16][4096]
    int*    yidx   = (int*)(pkey + 16 * 4096);
    int*    labels = yidx + 4096;
    float*  terms  = (float*)(labels + 4096);

    // fused casts
    cast_all<<<16384, 256, 0, stream>>>(x1, x2, W1, W2, xcatb, W1b, W2b);

    // h = xcat @ W1^T + b1 (M=4096,N=2048,K=2048), fused BN-stat partials
    gemm_bt2<<<512, 256, 0, stream>>>(xcatb, W1b, b1, hbuf, 16, 2048, 1 << 30, 0, 1, psA, psB, nullptr);
    bn_final2<<<16, 256, 0, stream>>>(psA, psB, mu, rinv);
    bn_apply<<<8192, 256, 0, stream>>>(hbuf, mu, rinv, gamma, beta, hnb);

    // o = hn @ W2^T + b2
    gemm_bt2<<<512, 256, 0, stream>>>(hnb, W2b, b2, hbuf, 16, 2048, 1 << 30, 0, 0, nullptr, nullptr, nullptr);

    // feat = normalize(o) -> bf16
    rownorm<<<4096, 256, 0, stream>>>(hbuf, featb);

    // sim = [feat1@feat1^T ; feat2@feat2^T], fused row-argmax partials
    gemm_bt2<<<512, 256, 0, stream>>>(featb, featb, nullptr, sim, 16, 2048, 2048, (long long)NN,
                                      2, nullptr, nullptr, pkey);
    argmax_combine<<<16, 256, 0, stream>>>(pkey, yidx);

    // CC -> loss
    cc_labels<<<2, 1024, 0, stream>>>(yidx, labels);
    loss_rows<<<4096, 256, 0, stream>>>(sim, labels, terms);
    final_reduce<<<1, 1024, 0, stream>>>(terms, (float*)d_out);
}